// Round 15
// baseline (498.229 us; speedup 1.0000x reference)
//
#include <hip/hip_runtime.h>
#include <hip/hip_bf16.h>

#define N_NODES 200000
#define N_EDGES 400000
#define HID 128

#define SHIFT 10                       // 1024 segments per bucket
#define NB_E 391                       // ceil(400000/1024)
#define NB_V 196                       // ceil(200000/1024)
#define CAP_E 6144                     // fixed slab capacity per e-bucket
#define CAP_V 10240                    // fixed slab capacity per v-bucket
#define BINSZ 4096                     // entries per bin block

typedef unsigned int u32;
typedef unsigned short u16;
typedef unsigned char u8;
typedef long long i64;
typedef __attribute__((ext_vector_type(4))) float f32x4;
typedef __attribute__((ext_vector_type(2))) float f32x2;

__device__ inline float sigmoidf(float v) { return 1.0f / (1.0f + __expf(-v)); }

// pack 4 f32 -> 4 fp8 (e4m3) in one u32
__device__ inline u32 pk4_fp8(float f0, float f1, float f2, float f3) {
  u32 v = __builtin_amdgcn_cvt_pk_fp8_f32(f0, f1, 0, false);
  v = __builtin_amdgcn_cvt_pk_fp8_f32(f2, f3, v, true);
  return v;
}

// accumulate 16 fp8 channels (one uint4) with weight wv into 8 f32x2 accs
__device__ inline void acc16_fp8(const uint4& q, float wv, f32x2* a) {
#pragma unroll
  for (int h = 0; h < 4; ++h) {
    u32 u = (&q.x)[h];
    a[h * 2 + 0] += __builtin_amdgcn_cvt_pk_f32_fp8(u, false) * wv;
    a[h * 2 + 1] += __builtin_amdgcn_cvt_pk_f32_fp8(u, true) * wv;
  }
}

// ---- bin (counting-sort staged, role-split grid) ------------------------------
// Blocks [0,nbBinE): e-side bin; [nbBinE, nbBinE+nbBinV): v-side bin;
// rest: mm14 (U = x0 @ w14, fp8 out) backfilling idle CUs.
// Bin: hist -> LDS prefix -> place into LDS staging SORTED by bucket (dst
// precomputed) -> flush coalesced. tmp entry: {(local_seg<<19)|idx, val_bits}.
__global__ __launch_bounds__(256) void bin_mm14_kernel(
    const int* __restrict__ rows, const int* __restrict__ cols,
    const float* __restrict__ vals, u32* __restrict__ bkE,
    u32* __restrict__ bkV, int2* __restrict__ tmp_e, int2* __restrict__ tmp_v,
    int nnz, int nbBinE, int nbBinV, const float* __restrict__ x0,
    const float* __restrict__ w14, u8* __restrict__ U, int N) {
  __shared__ int2 stage[BINSZ];        // 32 KB (mm14 aliases as ws)
  __shared__ u32 dsti[BINSZ];          // 16 KB
  __shared__ u32 h[NB_E];              // counts -> cursors
  __shared__ u32 pe[NB_E + 1];         // block-local prefix
  __shared__ u32 gb[NB_E];             // global slab base per bucket
  __shared__ u32 aux[256];
  const int tid = threadIdx.x;
  const int bid = blockIdx.x;

  if (bid >= nbBinE + nbBinV) {
    // ---- mm14 role ----
    float* ws = (float*)stage;
    for (int i = tid; i < 14 * HID; i += 256) ws[i] = w14[i];
    __syncthreads();
    const int row = (bid - nbBinE - nbBinV) * 8 + (tid >> 5);
    const int c4 = (tid & 31) << 2;
    if (row >= N) return;
    const float* xr = x0 + (size_t)row * 14;
    float a0 = 0.f, a1 = 0.f, a2 = 0.f, a3 = 0.f;
#pragma unroll
    for (int k = 0; k < 14; ++k) {
      const float xv = xr[k];
      const float* wr = ws + k * HID + c4;
      a0 = fmaf(xv, wr[0], a0);
      a1 = fmaf(xv, wr[1], a1);
      a2 = fmaf(xv, wr[2], a2);
      a3 = fmaf(xv, wr[3], a3);
    }
    *(u32*)(U + (size_t)row * HID + c4) = pk4_fp8(a0, a1, a2, a3);
    return;
  }

  // ---- bin role (one side per block) ----
  const bool ES = bid < nbBinE;
  const int blk = ES ? bid : bid - nbBinE;
  const int NB = ES ? NB_E : NB_V;
  const int CAP = ES ? CAP_E : CAP_V;
  const int* __restrict__ key = ES ? cols : rows;
  const int* __restrict__ oth = ES ? rows : cols;
  u32* __restrict__ bk = ES ? bkE : bkV;
  int2* __restrict__ tmp = ES ? tmp_e : tmp_v;

  for (int j = tid; j < NB; j += 256) h[j] = 0;
  __syncthreads();
  const int i0 = blk * BINSZ;
  const int total = min(BINSZ, nnz - i0);
#pragma unroll
  for (int k = 0; k < BINSZ / 256; ++k) {
    int i = i0 + k * 256 + tid;
    if (i < nnz) atomicAdd(&h[key[i] >> SHIFT], 1u);
  }
  __syncthreads();
  // exclusive prefix of h[0..NB) -> pe  (2 slots/thread, Hillis-Steele on aux)
  u32 a0 = (2 * tid < NB) ? h[2 * tid] : 0;
  u32 a1 = (2 * tid + 1 < NB) ? h[2 * tid + 1] : 0;
  u32 T = a0 + a1;
  aux[tid] = T;
  __syncthreads();
  for (int d = 1; d < 256; d <<= 1) {
    u32 x = (tid >= d) ? aux[tid - d] : 0;
    __syncthreads();
    aux[tid] += x;
    __syncthreads();
  }
  u32 off = aux[tid] - T;
  if (2 * tid < NB) pe[2 * tid] = off;
  if (2 * tid + 1 < NB) pe[2 * tid + 1] = off + a0;
  // global slab bases; reuse h as local cursor
  for (int j = tid; j < NB; j += 256) {
    u32 n = h[j];
    gb[j] = n ? atomicAdd(&bk[j], n) : 0;
    h[j] = 0;
  }
  __syncthreads();
#pragma unroll
  for (int k = 0; k < BINSZ / 256; ++k) {
    int i = i0 + k * 256 + tid;
    if (i < nnz) {
      int kk = key[i];
      int b = kk >> SHIFT;
      u32 lr = atomicAdd(&h[b], 1u);
      u32 pos = pe[b] + lr;
      stage[pos] = make_int2(((kk & 1023) << 19) | oth[i],
                             __float_as_int(vals[i]));
      dsti[pos] = (u32)b * CAP + gb[b] + lr;
    }
  }
  __syncthreads();
  // flush sorted-by-bucket -> coalesced scattered stores
  for (int t = tid; t < total; t += 256) tmp[dsti[t]] = stage[t];
}

// merged: block0 scans bkE, block1 scans bkV, block2 sentinels + pooled zero.
__global__ __launch_bounds__(512) void scan_all_kernel(
    u32* __restrict__ bkE, u32* __restrict__ bkV, u32* __restrict__ ptr_e,
    u32* __restrict__ ptr_v, u32* __restrict__ pooled, u32 nnz) {
  if (blockIdx.x == 2) {
    if (threadIdx.x < HID) pooled[threadIdx.x] = 0;
    if (threadIdx.x == 0) {
      bkE[NB_E] = nnz;
      bkV[NB_V] = nnz;
      ptr_e[N_EDGES] = nnz;
      ptr_v[N_NODES] = nnz;
    }
    return;
  }
  u32* blk = (blockIdx.x == 0) ? bkE : bkV;
  const int n = (blockIdx.x == 0) ? NB_E : NB_V;
  __shared__ u32 tmp[512];
  int t = threadIdx.x;
  u32 v = (t < n) ? blk[t] : 0;
  tmp[t] = v;
  __syncthreads();
  for (int d = 1; d < 512; d <<= 1) {
    u32 x = (t >= d) ? tmp[t - d] : 0;
    __syncthreads();
    tmp[t] += x;
    __syncthreads();
  }
  if (t < n) blk[t] = tmp[t] - v;
}

// Per bucket: LDS count + scan -> ptr, place entries from the bucket slab
// (L2-local), compute cards; EDGE side also computes denom + final weights.
template <bool EDGE>
__global__ __launch_bounds__(512) void build_kernel(
    const int2* __restrict__ tmp, int cap, const u32* __restrict__ bukBase,
    u32* __restrict__ ptr, int2* __restrict__ ent, float* __restrict__ card,
    const float* __restrict__ ncard, int S) {
  __shared__ u32 loc[1024];
  __shared__ u32 sstart[1024];
  __shared__ u32 aux[512];
  const int tid = threadIdx.x;
  const int c0 = blockIdx.x << SHIFT;
  const int nseg = min(1024, S - c0);
  const u32 eb = bukBase[blockIdx.x], ee = bukBase[blockIdx.x + 1];
  const u32 cnt = ee - eb;
  const int2* tp = tmp + (size_t)blockIdx.x * cap;
  loc[tid] = 0;
  loc[tid + 512] = 0;
  __syncthreads();
  for (u32 j = tid; j < cnt; j += 512)
    atomicAdd(&loc[(u32)tp[j].x >> 19], 1u);
  __syncthreads();
  u32 a0 = loc[2 * tid], a1 = loc[2 * tid + 1];
  u32 T = a0 + a1;
  aux[tid] = T;
  __syncthreads();
  for (int d = 1; d < 512; d <<= 1) {
    u32 x = (tid >= d) ? aux[tid - d] : 0;
    __syncthreads();
    aux[tid] += x;
    __syncthreads();
  }
  u32 off = aux[tid] - T;
  loc[2 * tid] = off;
  loc[2 * tid + 1] = off + a0;
  sstart[2 * tid] = off;
  sstart[2 * tid + 1] = off + a0;
  __syncthreads();
  for (int k = tid; k < nseg; k += 512) ptr[c0 + k] = eb + loc[k];
  __syncthreads();
  for (u32 j = tid; j < cnt; j += 512) {
    int2 e = tp[j];
    u32 s = (u32)e.x >> 19;
    u32 p = atomicAdd(&loc[s], 1u);
    ent[eb + p] = make_int2(e.x & 0x7FFFF, e.y);   // {idx, raw val}
  }
  __syncthreads();
  for (int k = tid; k < nseg; k += 512) {
    u32 s0 = eb + sstart[k], s1 = eb + loc[k];
    float s = 0.f;
    for (u32 j = s0; j < s1; ++j) s += __int_as_float(ent[j].y);
    float t = rsqrtf(s);
    card[c0 + k] = EDGE ? t * t * t : t;   // deg^-1.5 : deg^-0.5
    if (EDGE) {
      float d = 0.f;
      for (u32 j = s0; j < s1; ++j) {
        int2 en = ent[j];
        d += __int_as_float(en.y) * ncard[en.x];
      }
      float inv = 1.f / d;
      for (u32 j = s0; j < s1; ++j) {
        int2 en = ent[j];
        ent[j].y = __float_as_int(__int_as_float(en.y) * ncard[en.x] * inv);
      }
    }
  }
}

// v-side weights, 2 lanes per segment (shfl-combined denom).
__global__ __launch_bounds__(256) void segV_kernel(
    const u32* __restrict__ ptr_v, int2* __restrict__ ent_v,
    const float* __restrict__ e_card) {
  int t = blockIdx.x * 256 + threadIdx.x;
  int i = t >> 1;
  int half = t & 1;
  if (i >= N_NODES) return;
  u32 b = ptr_v[i], e = ptr_v[i + 1];
  float s = 0.f;
  for (u32 j = b + half; j < e; j += 2) {
    int2 en = ent_v[j];
    s += __int_as_float(en.y) * e_card[en.x];
  }
  s += __shfl_xor(s, 1);
  float inv = 1.f / s;
  for (u32 j = b + half; j < e; j += 2) {
    int2 en = ent_v[j];
    ent_v[j].y = __float_as_int(__int_as_float(en.y) * e_card[en.x] * inv);
  }
}

// ---- dense matmuls ----------------------------------------------------------

// load one 128x128 weight matrix as per-wave fp8 B-fragments
__device__ inline void load_wfrags(const float* __restrict__ w, int lo, int hi,
                                   i64 wf[8][4]) {
#pragma unroll
  for (int n = 0; n < 8; ++n)
#pragma unroll
    for (int t = 0; t < 4; ++t) {
      const float* wp = w + (size_t)(t * 32 + hi * 8) * HID + n * 16 + lo;
      u32 w0 = pk4_fp8(wp[0], wp[HID], wp[2 * HID], wp[3 * HID]);
      u32 w1 = pk4_fp8(wp[4 * HID], wp[5 * HID], wp[6 * HID], wp[7 * HID]);
      wf[n][t] = (i64)w0 | ((i64)w1 << 32);
    }
}

// buf[R,128] = [sigmoid](buf @ w [+ b]) in-place, fp8 MFMA; optional max-pool.
template <bool SIG, bool POOL>
__global__ __launch_bounds__(256, 1) void im128_mfma_kernel(
    u8* __restrict__ buf, const float* __restrict__ w,
    const float* __restrict__ b, u32* __restrict__ pooled, int R) {
  const int tid = threadIdx.x;
  const int wave = tid >> 6;
  const int lo = tid & 15;
  const int hi = (tid & 63) >> 4;
  i64 wf[8][4];
  load_wfrags(w, lo, hi, wf);
  float bias[8];
  if (SIG) {
#pragma unroll
    for (int n = 0; n < 8; ++n) bias[n] = b[n * 16 + lo];
  }
  float pm[8];
#pragma unroll
  for (int n = 0; n < 8; ++n) pm[n] = 0.f;

  for (int rb = blockIdx.x * 64 + wave * 16; rb < R; rb += gridDim.x * 64) {
    const u8* xp = buf + (size_t)(rb + lo) * HID + hi * 8;
    i64 a0 = *(const i64*)(xp);
    i64 a1 = *(const i64*)(xp + 32);
    i64 a2 = *(const i64*)(xp + 64);
    i64 a3 = *(const i64*)(xp + 96);
    u8* yp = buf + (size_t)(rb + hi * 4) * HID + lo;
#pragma unroll
    for (int n = 0; n < 8; ++n) {
      f32x4 c = {0.f, 0.f, 0.f, 0.f};
      c = __builtin_amdgcn_mfma_f32_16x16x32_fp8_fp8(a0, wf[n][0], c, 0, 0, 0);
      c = __builtin_amdgcn_mfma_f32_16x16x32_fp8_fp8(a1, wf[n][1], c, 0, 0, 0);
      c = __builtin_amdgcn_mfma_f32_16x16x32_fp8_fp8(a2, wf[n][2], c, 0, 0, 0);
      c = __builtin_amdgcn_mfma_f32_16x16x32_fp8_fp8(a3, wf[n][3], c, 0, 0, 0);
#pragma unroll
      for (int r = 0; r < 4; ++r) {
        float v = SIG ? sigmoidf(c[r] + bias[n]) : c[r];
        if (POOL) {
          pm[n] = fmaxf(pm[n], v);
        } else {
          u32 q = __builtin_amdgcn_cvt_pk_fp8_f32(v, v, 0, false);
          yp[(size_t)r * HID + n * 16] = (u8)q;
        }
      }
    }
  }

  if (POOL) {
    __shared__ u32 pmax[HID];
    for (int i = tid; i < HID; i += 256) pmax[i] = 0;
    __syncthreads();
#pragma unroll
    for (int n = 0; n < 8; ++n)
      atomicMax(&pmax[n * 16 + lo], __float_as_uint(pm[n]));
    __syncthreads();
    if (tid < HID) atomicMax(&pooled[tid], pmax[tid]);
  }
}

// ---- gathers ----------------------------------------------------------------

// dst[r][:] = [sigmoid](sum_j w[j] * src[idx[j]][:] [+ b]), fp8 in/out.
template <bool SIG>
__global__ __launch_bounds__(256) void gather128_kernel(
    const u32* __restrict__ ptr, const int2* __restrict__ ent,
    const u8* __restrict__ src, const float* __restrict__ b,
    u8* __restrict__ dst, int S) {
  long long t = (long long)blockIdx.x * 256 + threadIdx.x;
  int r = (int)(t >> 3);
  if (r >= S) return;
  const int c16 = (int)(t & 7) << 4;  // 16 channels (16 bytes)
  u32 beg = ptr[r], end = ptr[r + 1];
  f32x2 a[8];
#pragma unroll
  for (int i = 0; i < 8; ++i) a[i] = (f32x2){0.f, 0.f};
  u32 j = beg;
  for (; j + 2 <= end; j += 2) {
    int2 e0 = ent[j];
    int2 e1 = ent[j + 1];
    const uint4 q0 = *(const uint4*)(src + (size_t)e0.x * HID + c16);
    const uint4 q1 = *(const uint4*)(src + (size_t)e1.x * HID + c16);
    acc16_fp8(q0, __int_as_float(e0.y), a);
    acc16_fp8(q1, __int_as_float(e1.y), a);
  }
  if (j < end) {
    int2 e0 = ent[j];
    const uint4 q0 = *(const uint4*)(src + (size_t)e0.x * HID + c16);
    acc16_fp8(q0, __int_as_float(e0.y), a);
  }
  float o[16];
#pragma unroll
  for (int h = 0; h < 4; ++h) {
    o[h * 4 + 0] = a[h * 2 + 0].x;
    o[h * 4 + 1] = a[h * 2 + 0].y;
    o[h * 4 + 2] = a[h * 2 + 1].x;
    o[h * 4 + 3] = a[h * 2 + 1].y;
  }
  if (SIG) {
#pragma unroll
    for (int h = 0; h < 4; ++h) {
      float4 bb = *(const float4*)(b + c16 + h * 4);
      o[h * 4 + 0] = sigmoidf(o[h * 4 + 0] + bb.x);
      o[h * 4 + 1] = sigmoidf(o[h * 4 + 1] + bb.y);
      o[h * 4 + 2] = sigmoidf(o[h * 4 + 2] + bb.z);
      o[h * 4 + 3] = sigmoidf(o[h * 4 + 3] + bb.w);
    }
  }
  uint4 pk;
  pk.x = pk4_fp8(o[0], o[1], o[2], o[3]);
  pk.y = pk4_fp8(o[4], o[5], o[6], o[7]);
  pk.z = pk4_fp8(o[8], o[9], o[10], o[11]);
  pk.w = pk4_fp8(o[12], o[13], o[14], o[15]);
  *(uint4*)(dst + (size_t)r * HID + c16) = pk;
}

// ---- head ---------------------------------------------------------------

__global__ __launch_bounds__(128) void final_kernel(
    const u32* __restrict__ pooled, const float* __restrict__ lin_w,
    const float* __restrict__ lin_b, float* __restrict__ out) {
  __shared__ float red[64];
  int t = threadIdx.x;
  float v = __uint_as_float(pooled[t]) * lin_w[t];
  if (t >= 64) red[t - 64] = v;
  __syncthreads();
  if (t < 64) {
    v += red[t];
#pragma unroll
    for (int off = 32; off > 0; off >>= 1) v += __shfl_down(v, off);
    if (t == 0) out[0] = v + lin_b[0];
  }
}

__global__ void diag_kernel(float* out, float v) { out[0] = v; }

// ---- launch -----------------------------------------------------------------

extern "C" void kernel_launch(void* const* d_in, const int* in_sizes, int n_in,
                              void* d_out, int out_size, void* d_ws, size_t ws_size,
                              hipStream_t stream) {
  const float* x0     = (const float*)d_in[0];
  const int*   rows   = (const int*)d_in[1];
  const int*   cols   = (const int*)d_in[2];
  const float* vals   = (const float*)d_in[3];
  const float* w0_l1  = (const float*)d_in[4];
  const float* w1_l1  = (const float*)d_in[5];
  const float* b1_l1  = (const float*)d_in[6];
  const float* b0_l1  = (const float*)d_in[7];
  const float* w0_l2  = (const float*)d_in[8];
  const float* w1_l2  = (const float*)d_in[9];
  const float* b1_l2  = (const float*)d_in[10];
  const float* b0_l2  = (const float*)d_in[11];
  const float* lin_w  = (const float*)d_in[12];
  const float* lin_b  = (const float*)d_in[13];
  float* out = (float*)d_out;
  const int nnz = in_sizes[1];

  char* wsp = (char*)d_ws;
  size_t off = 0;
  auto carve = [&](size_t bytes) -> char* {
    char* p = wsp + off;
    off = (off + bytes + 511) & ~(size_t)511;
    return p;
  };
  float* n_card  = (float*)carve((size_t)N_NODES * 4);
  float* e_card  = (float*)carve((size_t)N_EDGES * 4);
  u32*   ptr_v   = (u32*)carve((size_t)(N_NODES + 1) * 4);
  u32*   ptr_e   = (u32*)carve((size_t)(N_EDGES + 1) * 4);
  u32*   bkE     = (u32*)carve((NB_E + 1) * 4);   // counts -> bases (adjacent:
  u32*   bkV     = (u32*)carve((NB_V + 1) * 4);   //  one memset covers both)
  int2*  ent_v   = (int2*)carve((size_t)nnz * 8);   // {idx, val->weight}
  int2*  ent_e   = (int2*)carve((size_t)nnz * 8);
  u32*   pooled  = (u32*)carve(HID * 4);
  u8*    bufN    = (u8*)carve((size_t)N_NODES * HID);        // 25.6 MB fp8
  u8*    bufE    = (u8*)carve((size_t)N_EDGES * HID);        // 51.2 MB fp8
  int2*  tmp_e   = (int2*)carve((size_t)NB_E * CAP_E * 8);   // 19.2 MB slabs
  int2*  tmp_v   = (int2*)carve((size_t)NB_V * CAP_V * 8);   // 16.1 MB slabs

  if (off > ws_size) {  // diagnostic: report ws MB via absmax instead of crashing
    diag_kernel<<<1, 1, 0, stream>>>(out, (float)(ws_size >> 20));
    return;
  }

  // single memset spanning bkE..bkV (adjacent carves incl. 512B padding)
  hipMemsetAsync(bkE, 0, (size_t)((char*)ent_v - (char*)bkE), stream);

  const int nbBin = (nnz + BINSZ - 1) / BINSZ;   // per side
  const int nbMM14 = (N_NODES + 7) / 8;

  // CSR build: counting-sort bin (+ mm14 backfill) -> scans -> build -> segV
  bin_mm14_kernel<<<2 * nbBin + nbMM14, 256, 0, stream>>>(
      rows, cols, vals, bkE, bkV, tmp_e, tmp_v, nnz, nbBin, nbBin,
      x0, w0_l1, bufN, N_NODES);
  scan_all_kernel<<<3, 512, 0, stream>>>(bkE, bkV, ptr_e, ptr_v, pooled, (u32)nnz);
  build_kernel<false><<<NB_V, 512, 0, stream>>>(tmp_v, CAP_V, bkV, ptr_v,
                                                ent_v, n_card, nullptr, N_NODES);
  build_kernel<true><<<NB_E, 512, 0, stream>>>(tmp_e, CAP_E, bkE, ptr_e,
                                               ent_e, e_card, n_card, N_EDGES);
  segV_kernel<<<(2 * N_NODES + 255) / 256, 256, 0, stream>>>(ptr_v, ent_v, e_card);

  const int nbE8 = (int)(((long long)N_EDGES * 8 + 255) / 256);
  const int nbN8 = (int)(((long long)N_NODES * 8 + 255) / 256);

  // ---- layer 1 ----
  gather128_kernel<true><<<nbE8, 256, 0, stream>>>(ptr_e, ent_e, bufN,
                                                   b1_l1, bufE, N_EDGES);
  gather128_kernel<false><<<nbN8, 256, 0, stream>>>(ptr_v, ent_v, bufE,
                                                    nullptr, bufN, N_NODES);
  im128_mfma_kernel<true, false><<<1024, 256, 0, stream>>>(bufN, w1_l1, b0_l1,
                                                           nullptr, N_NODES);

  // ---- layer 2 ----
  im128_mfma_kernel<false, false><<<1024, 256, 0, stream>>>(bufN, w0_l2, nullptr,
                                                            nullptr, N_NODES);
  gather128_kernel<true><<<nbE8, 256, 0, stream>>>(ptr_e, ent_e, bufN,
                                                   b1_l2, bufE, N_EDGES);
  gather128_kernel<false><<<nbN8, 256, 0, stream>>>(ptr_v, ent_v, bufE,
                                                    nullptr, bufN, N_NODES);
  im128_mfma_kernel<true, true><<<1024, 256, 0, stream>>>(bufN, w1_l2, b0_l2,
                                                          pooled, N_NODES);

  // ---- head ----
  final_kernel<<<1, 128, 0, stream>>>(pooled, lin_w, lin_b, out);
}

// Round 16
// 478.314 us; speedup vs baseline: 1.0416x; 1.0416x over previous
//
#include <hip/hip_runtime.h>
#include <hip/hip_bf16.h>

#define N_NODES 200000
#define N_EDGES 400000
#define HID 128

#define SHIFT 10                       // 1024 segments per bucket
#define NB_E 391                       // ceil(400000/1024)
#define NB_V 196                       // ceil(200000/1024)
#define NBT (NB_E + NB_V)              // 587
#define CAP_E 6144                     // fixed slab capacity per e-bucket
#define CAP_V 10240                    // fixed slab capacity per v-bucket
#define BINSZ 4096                     // entries per bin block

typedef unsigned int u32;
typedef unsigned short u16;
typedef unsigned char u8;
typedef long long i64;
typedef __attribute__((ext_vector_type(4))) float f32x4;
typedef __attribute__((ext_vector_type(2))) float f32x2;

__device__ inline float sigmoidf(float v) { return 1.0f / (1.0f + __expf(-v)); }

// pack 4 f32 -> 4 fp8 (e4m3) in one u32
__device__ inline u32 pk4_fp8(float f0, float f1, float f2, float f3) {
  u32 v = __builtin_amdgcn_cvt_pk_fp8_f32(f0, f1, 0, false);
  v = __builtin_amdgcn_cvt_pk_fp8_f32(f2, f3, v, true);
  return v;
}

// accumulate 16 fp8 channels (one uint4) with weight wv into 8 f32x2 accs
__device__ inline void acc16_fp8(const uint4& q, float wv, f32x2* a) {
#pragma unroll
  for (int h = 0; h < 4; ++h) {
    u32 u = (&q.x)[h];
    a[h * 2 + 0] += __builtin_amdgcn_cvt_pk_f32_fp8(u, false) * wv;
    a[h * 2 + 1] += __builtin_amdgcn_cvt_pk_f32_fp8(u, true) * wv;
  }
}

// ---- bin (+ fused independent mm14) — R14-proven structure --------------------
__global__ __launch_bounds__(256) void bin_mm14_kernel(
    const int* __restrict__ rows, const int* __restrict__ cols,
    const float* __restrict__ vals, u32* __restrict__ bkE,
    u32* __restrict__ bkV, int2* __restrict__ tmp_e, int2* __restrict__ tmp_v,
    int nnz, int nbBin, const float* __restrict__ x0,
    const float* __restrict__ w14, u8* __restrict__ U, int N) {
  __shared__ u32 smem[14 * HID];   // 7168 B: ws (mm14) or h+base (bin)
  const int tid = threadIdx.x;

  if ((int)blockIdx.x >= nbBin) {
    // ---- mm14 role ----
    float* ws = (float*)smem;
    for (int i = tid; i < 14 * HID; i += 256) ws[i] = w14[i];
    __syncthreads();
    const int row = ((int)blockIdx.x - nbBin) * 8 + (tid >> 5);
    const int c4 = (tid & 31) << 2;
    if (row >= N) return;
    const float* xr = x0 + (size_t)row * 14;
    float a0 = 0.f, a1 = 0.f, a2 = 0.f, a3 = 0.f;
#pragma unroll
    for (int k = 0; k < 14; ++k) {
      const float xv = xr[k];
      const float* wr = ws + k * HID + c4;
      a0 = fmaf(xv, wr[0], a0);
      a1 = fmaf(xv, wr[1], a1);
      a2 = fmaf(xv, wr[2], a2);
      a3 = fmaf(xv, wr[3], a3);
    }
    *(u32*)(U + (size_t)row * HID + c4) = pk4_fp8(a0, a1, a2, a3);
    return;
  }

  // ---- bin role ----
  u32* h = smem;
  u32* base = smem + NBT;
  for (int j = tid; j < NBT; j += 256) h[j] = 0;
  __syncthreads();
  const int i0 = blockIdx.x * BINSZ;
  for (int k = 0; k < BINSZ / 256; ++k) {
    int i = i0 + k * 256 + tid;
    if (i < nnz) {
      atomicAdd(&h[cols[i] >> SHIFT], 1u);
      atomicAdd(&h[NB_E + (rows[i] >> SHIFT)], 1u);
    }
  }
  __syncthreads();
  for (int j = tid; j < NBT; j += 256) {
    u32 n = h[j];
    base[j] = n ? ((j < NB_E) ? atomicAdd(&bkE[j], n)
                              : atomicAdd(&bkV[j - NB_E], n))
                : 0;
    h[j] = 0;
  }
  __syncthreads();
  for (int k = 0; k < BINSZ / 256; ++k) {
    int i = i0 + k * 256 + tid;
    if (i < nnz) {
      int c = cols[i], r = rows[i];
      int vb = __float_as_int(vals[i]);
      int be = c >> SHIFT;
      int bv = NB_E + (r >> SHIFT);
      u32 le = atomicAdd(&h[be], 1u);
      tmp_e[(size_t)be * CAP_E + base[be] + le] =
          make_int2(((c & 1023) << 19) | r, vb);
      u32 lv = atomicAdd(&h[bv], 1u);
      tmp_v[(size_t)(bv - NB_E) * CAP_V + base[bv] + lv] =
          make_int2(((r & 1023) << 19) | c, vb);
    }
  }
}

// merged: block0 scans bkE, block1 scans bkV, block2 sentinels + pooled zero.
__global__ __launch_bounds__(512) void scan_all_kernel(
    u32* __restrict__ bkE, u32* __restrict__ bkV, u32* __restrict__ ptr_e,
    u32* __restrict__ ptr_v, u32* __restrict__ pooled, u32 nnz) {
  if (blockIdx.x == 2) {
    if (threadIdx.x < HID) pooled[threadIdx.x] = 0;
    if (threadIdx.x == 0) {
      bkE[NB_E] = nnz;
      bkV[NB_V] = nnz;
      ptr_e[N_EDGES] = nnz;
      ptr_v[N_NODES] = nnz;
    }
    return;
  }
  u32* blk = (blockIdx.x == 0) ? bkE : bkV;
  const int n = (blockIdx.x == 0) ? NB_E : NB_V;
  __shared__ u32 tmp[512];
  int t = threadIdx.x;
  u32 v = (t < n) ? blk[t] : 0;
  tmp[t] = v;
  __syncthreads();
  for (int d = 1; d < 512; d <<= 1) {
    u32 x = (t >= d) ? tmp[t - d] : 0;
    __syncthreads();
    tmp[t] += x;
    __syncthreads();
  }
  if (t < n) blk[t] = tmp[t] - v;
}

// Per bucket: LDS count + scan -> ptr, place entries (L2-local), compute cards;
// EDGE side also computes denom + final weights. Also counts per-length
// histogram (16 clamped bins) into lcnt for the divergence-sort permutation.
template <bool EDGE>
__global__ __launch_bounds__(512) void build_kernel(
    const int2* __restrict__ tmp, int cap, const u32* __restrict__ bukBase,
    u32* __restrict__ ptr, int2* __restrict__ ent, float* __restrict__ card,
    const float* __restrict__ ncard, u32* __restrict__ lcnt, int S) {
  __shared__ u32 loc[1024];
  __shared__ u32 sstart[1024];
  __shared__ u32 aux[512];
  __shared__ u32 lh[16];
  const int tid = threadIdx.x;
  const int c0 = blockIdx.x << SHIFT;
  const int nseg = min(1024, S - c0);
  const u32 eb = bukBase[blockIdx.x], ee = bukBase[blockIdx.x + 1];
  const u32 cnt = ee - eb;
  const int2* tp = tmp + (size_t)blockIdx.x * cap;
  loc[tid] = 0;
  loc[tid + 512] = 0;
  if (tid < 16) lh[tid] = 0;
  __syncthreads();
  for (u32 j = tid; j < cnt; j += 512)
    atomicAdd(&loc[(u32)tp[j].x >> 19], 1u);
  __syncthreads();
  u32 a0 = loc[2 * tid], a1 = loc[2 * tid + 1];
  u32 T = a0 + a1;
  aux[tid] = T;
  __syncthreads();
  for (int d = 1; d < 512; d <<= 1) {
    u32 x = (tid >= d) ? aux[tid - d] : 0;
    __syncthreads();
    aux[tid] += x;
    __syncthreads();
  }
  u32 off = aux[tid] - T;
  loc[2 * tid] = off;
  loc[2 * tid + 1] = off + a0;
  sstart[2 * tid] = off;
  sstart[2 * tid + 1] = off + a0;
  __syncthreads();
  for (int k = tid; k < nseg; k += 512) ptr[c0 + k] = eb + loc[k];
  __syncthreads();
  for (u32 j = tid; j < cnt; j += 512) {
    int2 e = tp[j];
    u32 s = (u32)e.x >> 19;
    u32 p = atomicAdd(&loc[s], 1u);
    ent[eb + p] = make_int2(e.x & 0x7FFFF, e.y);   // {idx, raw val}
  }
  __syncthreads();
  for (int k = tid; k < nseg; k += 512) {
    u32 len = loc[k] - sstart[k];
    atomicAdd(&lh[min(len - 1, 15u)], 1u);
    u32 s0 = eb + sstart[k], s1 = eb + loc[k];
    float s = 0.f;
    for (u32 j = s0; j < s1; ++j) s += __int_as_float(ent[j].y);
    float t = rsqrtf(s);
    card[c0 + k] = EDGE ? t * t * t : t;   // deg^-1.5 : deg^-0.5
    if (EDGE) {
      float d = 0.f;
      for (u32 j = s0; j < s1; ++j) {
        int2 en = ent[j];
        d += __int_as_float(en.y) * ncard[en.x];
      }
      float inv = 1.f / d;
      for (u32 j = s0; j < s1; ++j) {
        int2 en = ent[j];
        ent[j].y = __float_as_int(__int_as_float(en.y) * ncard[en.x] * inv);
      }
    }
  }
  __syncthreads();
  if (tid < 16 && lh[tid]) atomicAdd(&lcnt[tid], lh[tid]);
}

// exclusive scan of the two 16-bin length histograms (cursor arrays)
__global__ void scan32_kernel(u32* __restrict__ lcntE, u32* __restrict__ lcntV) {
  u32* a = (threadIdx.x == 0) ? lcntE : lcntV;
  u32 s = 0;
  for (int i = 0; i < 16; ++i) {
    u32 v = a[i];
    a[i] = s;
    s += v;
  }
}

// place row ids into perm grouped by clamped segment length (16 buckets).
__global__ __launch_bounds__(256) void perm_place_kernel(
    const u32* __restrict__ ptr_e, const u32* __restrict__ ptr_v,
    u32* __restrict__ curE, u32* __restrict__ curV,
    u32* __restrict__ permE, u32* __restrict__ permV, int nbE) {
  const int bid = blockIdx.x;
  const bool ES = bid < nbE;
  const u32* ptr = ES ? ptr_e : ptr_v;
  u32* cur = ES ? curE : curV;
  u32* perm = ES ? permE : permV;
  const int S = ES ? N_EDGES : N_NODES;
  const int i = (ES ? bid : bid - nbE) * 256 + threadIdx.x;
  __shared__ u32 lh[16];
  __shared__ u32 base[16];
  if (threadIdx.x < 16) lh[threadIdx.x] = 0;
  __syncthreads();
  int b = 0;
  u32 lr = 0;
  if (i < S) {
    u32 len = ptr[i + 1] - ptr[i];
    b = (int)min(len - 1, 15u);
    lr = atomicAdd(&lh[b], 1u);
  }
  __syncthreads();
  if (threadIdx.x < 16)
    base[threadIdx.x] =
        lh[threadIdx.x] ? atomicAdd(&cur[threadIdx.x], lh[threadIdx.x]) : 0;
  __syncthreads();
  if (i < S) perm[base[b] + lr] = (u32)i;
}

// v-side weights, 2 lanes per segment (shfl-combined denom).
__global__ __launch_bounds__(256) void segV_kernel(
    const u32* __restrict__ ptr_v, int2* __restrict__ ent_v,
    const float* __restrict__ e_card) {
  int t = blockIdx.x * 256 + threadIdx.x;
  int i = t >> 1;
  int half = t & 1;
  if (i >= N_NODES) return;
  u32 b = ptr_v[i], e = ptr_v[i + 1];
  float s = 0.f;
  for (u32 j = b + half; j < e; j += 2) {
    int2 en = ent_v[j];
    s += __int_as_float(en.y) * e_card[en.x];
  }
  s += __shfl_xor(s, 1);
  float inv = 1.f / s;
  for (u32 j = b + half; j < e; j += 2) {
    int2 en = ent_v[j];
    ent_v[j].y = __float_as_int(__int_as_float(en.y) * e_card[en.x] * inv);
  }
}

// ---- dense matmuls ----------------------------------------------------------

// load one 128x128 weight matrix as per-wave fp8 B-fragments
__device__ inline void load_wfrags(const float* __restrict__ w, int lo, int hi,
                                   i64 wf[8][4]) {
#pragma unroll
  for (int n = 0; n < 8; ++n)
#pragma unroll
    for (int t = 0; t < 4; ++t) {
      const float* wp = w + (size_t)(t * 32 + hi * 8) * HID + n * 16 + lo;
      u32 w0 = pk4_fp8(wp[0], wp[HID], wp[2 * HID], wp[3 * HID]);
      u32 w1 = pk4_fp8(wp[4 * HID], wp[5 * HID], wp[6 * HID], wp[7 * HID]);
      wf[n][t] = (i64)w0 | ((i64)w1 << 32);
    }
}

// buf[R,128] = [sigmoid](buf @ w [+ b]) in-place, fp8 MFMA; optional max-pool.
template <bool SIG, bool POOL>
__global__ __launch_bounds__(256, 1) void im128_mfma_kernel(
    u8* __restrict__ buf, const float* __restrict__ w,
    const float* __restrict__ b, u32* __restrict__ pooled, int R) {
  const int tid = threadIdx.x;
  const int wave = tid >> 6;
  const int lo = tid & 15;
  const int hi = (tid & 63) >> 4;
  i64 wf[8][4];
  load_wfrags(w, lo, hi, wf);
  float bias[8];
  if (SIG) {
#pragma unroll
    for (int n = 0; n < 8; ++n) bias[n] = b[n * 16 + lo];
  }
  float pm[8];
#pragma unroll
  for (int n = 0; n < 8; ++n) pm[n] = 0.f;

  for (int rb = blockIdx.x * 64 + wave * 16; rb < R; rb += gridDim.x * 64) {
    const u8* xp = buf + (size_t)(rb + lo) * HID + hi * 8;
    i64 a0 = *(const i64*)(xp);
    i64 a1 = *(const i64*)(xp + 32);
    i64 a2 = *(const i64*)(xp + 64);
    i64 a3 = *(const i64*)(xp + 96);
    u8* yp = buf + (size_t)(rb + hi * 4) * HID + lo;
#pragma unroll
    for (int n = 0; n < 8; ++n) {
      f32x4 c = {0.f, 0.f, 0.f, 0.f};
      c = __builtin_amdgcn_mfma_f32_16x16x32_fp8_fp8(a0, wf[n][0], c, 0, 0, 0);
      c = __builtin_amdgcn_mfma_f32_16x16x32_fp8_fp8(a1, wf[n][1], c, 0, 0, 0);
      c = __builtin_amdgcn_mfma_f32_16x16x32_fp8_fp8(a2, wf[n][2], c, 0, 0, 0);
      c = __builtin_amdgcn_mfma_f32_16x16x32_fp8_fp8(a3, wf[n][3], c, 0, 0, 0);
#pragma unroll
      for (int r = 0; r < 4; ++r) {
        float v = SIG ? sigmoidf(c[r] + bias[n]) : c[r];
        if (POOL) {
          pm[n] = fmaxf(pm[n], v);
        } else {
          u32 q = __builtin_amdgcn_cvt_pk_fp8_f32(v, v, 0, false);
          yp[(size_t)r * HID + n * 16] = (u8)q;
        }
      }
    }
  }

  if (POOL) {
    __shared__ u32 pmax[HID];
    for (int i = tid; i < HID; i += 256) pmax[i] = 0;
    __syncthreads();
#pragma unroll
    for (int n = 0; n < 8; ++n)
      atomicMax(&pmax[n * 16 + lo], __float_as_uint(pm[n]));
    __syncthreads();
    if (tid < HID) atomicMax(&pooled[tid], pmax[tid]);
  }
}

// ---- gathers (length-sorted row order via perm) -------------------------------

// dst[perm[rid]][:] = [sigmoid](sum_j w[j] * src[idx[j]][:] [+ b]), fp8 in/out.
template <bool SIG>
__global__ __launch_bounds__(256) void gather128_kernel(
    const u32* __restrict__ ptr, const int2* __restrict__ ent,
    const u32* __restrict__ perm, const u8* __restrict__ src,
    const float* __restrict__ b, u8* __restrict__ dst, int S) {
  long long t = (long long)blockIdx.x * 256 + threadIdx.x;
  int rid = (int)(t >> 3);
  if (rid >= S) return;
  const int r = (int)perm[rid];
  const int c16 = (int)(t & 7) << 4;  // 16 channels (16 bytes)
  u32 beg = ptr[r], end = ptr[r + 1];
  f32x2 a[8];
#pragma unroll
  for (int i = 0; i < 8; ++i) a[i] = (f32x2){0.f, 0.f};
  u32 j = beg;
  for (; j + 2 <= end; j += 2) {
    int2 e0 = ent[j];
    int2 e1 = ent[j + 1];
    const uint4 q0 = *(const uint4*)(src + (size_t)e0.x * HID + c16);
    const uint4 q1 = *(const uint4*)(src + (size_t)e1.x * HID + c16);
    acc16_fp8(q0, __int_as_float(e0.y), a);
    acc16_fp8(q1, __int_as_float(e1.y), a);
  }
  if (j < end) {
    int2 e0 = ent[j];
    const uint4 q0 = *(const uint4*)(src + (size_t)e0.x * HID + c16);
    acc16_fp8(q0, __int_as_float(e0.y), a);
  }
  float o[16];
#pragma unroll
  for (int h = 0; h < 4; ++h) {
    o[h * 4 + 0] = a[h * 2 + 0].x;
    o[h * 4 + 1] = a[h * 2 + 0].y;
    o[h * 4 + 2] = a[h * 2 + 1].x;
    o[h * 4 + 3] = a[h * 2 + 1].y;
  }
  if (SIG) {
#pragma unroll
    for (int h = 0; h < 4; ++h) {
      float4 bb = *(const float4*)(b + c16 + h * 4);
      o[h * 4 + 0] = sigmoidf(o[h * 4 + 0] + bb.x);
      o[h * 4 + 1] = sigmoidf(o[h * 4 + 1] + bb.y);
      o[h * 4 + 2] = sigmoidf(o[h * 4 + 2] + bb.z);
      o[h * 4 + 3] = sigmoidf(o[h * 4 + 3] + bb.w);
    }
  }
  uint4 pk;
  pk.x = pk4_fp8(o[0], o[1], o[2], o[3]);
  pk.y = pk4_fp8(o[4], o[5], o[6], o[7]);
  pk.z = pk4_fp8(o[8], o[9], o[10], o[11]);
  pk.w = pk4_fp8(o[12], o[13], o[14], o[15]);
  *(uint4*)(dst + (size_t)r * HID + c16) = pk;
}

// ---- head ---------------------------------------------------------------

__global__ __launch_bounds__(128) void final_kernel(
    const u32* __restrict__ pooled, const float* __restrict__ lin_w,
    const float* __restrict__ lin_b, float* __restrict__ out) {
  __shared__ float red[64];
  int t = threadIdx.x;
  float v = __uint_as_float(pooled[t]) * lin_w[t];
  if (t >= 64) red[t - 64] = v;
  __syncthreads();
  if (t < 64) {
    v += red[t];
#pragma unroll
    for (int off = 32; off > 0; off >>= 1) v += __shfl_down(v, off);
    if (t == 0) out[0] = v + lin_b[0];
  }
}

__global__ void diag_kernel(float* out, float v) { out[0] = v; }

// ---- launch -----------------------------------------------------------------

extern "C" void kernel_launch(void* const* d_in, const int* in_sizes, int n_in,
                              void* d_out, int out_size, void* d_ws, size_t ws_size,
                              hipStream_t stream) {
  const float* x0     = (const float*)d_in[0];
  const int*   rows   = (const int*)d_in[1];
  const int*   cols   = (const int*)d_in[2];
  const float* vals   = (const float*)d_in[3];
  const float* w0_l1  = (const float*)d_in[4];
  const float* w1_l1  = (const float*)d_in[5];
  const float* b1_l1  = (const float*)d_in[6];
  const float* b0_l1  = (const float*)d_in[7];
  const float* w0_l2  = (const float*)d_in[8];
  const float* w1_l2  = (const float*)d_in[9];
  const float* b1_l2  = (const float*)d_in[10];
  const float* b0_l2  = (const float*)d_in[11];
  const float* lin_w  = (const float*)d_in[12];
  const float* lin_b  = (const float*)d_in[13];
  float* out = (float*)d_out;
  const int nnz = in_sizes[1];

  char* wsp = (char*)d_ws;
  size_t off = 0;
  auto carve = [&](size_t bytes) -> char* {
    char* p = wsp + off;
    off = (off + bytes + 511) & ~(size_t)511;
    return p;
  };
  float* n_card  = (float*)carve((size_t)N_NODES * 4);
  float* e_card  = (float*)carve((size_t)N_EDGES * 4);
  u32*   ptr_v   = (u32*)carve((size_t)(N_NODES + 1) * 4);
  u32*   ptr_e   = (u32*)carve((size_t)(N_EDGES + 1) * 4);
  u32*   bkE     = (u32*)carve((NB_E + 1) * 4);   // counts -> bases; zeroed by
  u32*   bkV     = (u32*)carve((NB_V + 1) * 4);   //  the single memset below
  u32*   lcntE   = (u32*)carve(16 * 4);           // length hist -> cursors
  u32*   lcntV   = (u32*)carve(16 * 4);
  int2*  ent_v   = (int2*)carve((size_t)nnz * 8);   // {idx, val->weight}
  int2*  ent_e   = (int2*)carve((size_t)nnz * 8);
  u32*   permE   = (u32*)carve((size_t)N_EDGES * 4);
  u32*   permV   = (u32*)carve((size_t)N_NODES * 4);
  u32*   pooled  = (u32*)carve(HID * 4);
  u8*    bufN    = (u8*)carve((size_t)N_NODES * HID);        // 25.6 MB fp8
  u8*    bufE    = (u8*)carve((size_t)N_EDGES * HID);        // 51.2 MB fp8
  int2*  tmp_e   = (int2*)carve((size_t)NB_E * CAP_E * 8);   // 19.2 MB slabs
  int2*  tmp_v   = (int2*)carve((size_t)NB_V * CAP_V * 8);   // 16.1 MB slabs

  if (off > ws_size) {  // diagnostic: report ws MB via absmax instead of crashing
    diag_kernel<<<1, 1, 0, stream>>>(out, (float)(ws_size >> 20));
    return;
  }

  // single memset spanning bkE..lcntV (adjacent carves incl. padding)
  hipMemsetAsync(bkE, 0, (size_t)((char*)ent_v - (char*)bkE), stream);

  const int nbBin = (nnz + BINSZ - 1) / BINSZ;
  const int nbMM14 = (N_NODES + 7) / 8;
  const int nbPermE = (N_EDGES + 255) / 256;
  const int nbPermV = (N_NODES + 255) / 256;

  // CSR build (+ mm14 backfill) -> scans -> build(+len hist) -> perm -> segV
  bin_mm14_kernel<<<nbBin + nbMM14, 256, 0, stream>>>(
      rows, cols, vals, bkE, bkV, tmp_e, tmp_v, nnz, nbBin,
      x0, w0_l1, bufN, N_NODES);
  scan_all_kernel<<<3, 512, 0, stream>>>(bkE, bkV, ptr_e, ptr_v, pooled, (u32)nnz);
  build_kernel<false><<<NB_V, 512, 0, stream>>>(tmp_v, CAP_V, bkV, ptr_v, ent_v,
                                                n_card, nullptr, lcntV, N_NODES);
  build_kernel<true><<<NB_E, 512, 0, stream>>>(tmp_e, CAP_E, bkE, ptr_e, ent_e,
                                               e_card, n_card, lcntE, N_EDGES);
  scan32_kernel<<<1, 2, 0, stream>>>(lcntE, lcntV);
  perm_place_kernel<<<nbPermE + nbPermV, 256, 0, stream>>>(
      ptr_e, ptr_v, lcntE, lcntV, permE, permV, nbPermE);
  segV_kernel<<<(2 * N_NODES + 255) / 256, 256, 0, stream>>>(ptr_v, ent_v, e_card);

  const int nbE8 = (int)(((long long)N_EDGES * 8 + 255) / 256);
  const int nbN8 = (int)(((long long)N_NODES * 8 + 255) / 256);

  // ---- layer 1 ----
  gather128_kernel<true><<<nbE8, 256, 0, stream>>>(ptr_e, ent_e, permE, bufN,
                                                   b1_l1, bufE, N_EDGES);
  gather128_kernel<false><<<nbN8, 256, 0, stream>>>(ptr_v, ent_v, permV, bufE,
                                                    nullptr, bufN, N_NODES);
  im128_mfma_kernel<true, false><<<1024, 256, 0, stream>>>(bufN, w1_l1, b0_l1,
                                                           nullptr, N_NODES);

  // ---- layer 2 ----
  im128_mfma_kernel<false, false><<<1024, 256, 0, stream>>>(bufN, w0_l2, nullptr,
                                                            nullptr, N_NODES);
  gather128_kernel<true><<<nbE8, 256, 0, stream>>>(ptr_e, ent_e, permE, bufN,
                                                   b1_l2, bufE, N_EDGES);
  gather128_kernel<false><<<nbN8, 256, 0, stream>>>(ptr_v, ent_v, permV, bufE,
                                                    nullptr, bufN, N_NODES);
  im128_mfma_kernel<true, true><<<1024, 256, 0, stream>>>(bufN, w1_l2, b0_l2,
                                                          pooled, N_NODES);

  // ---- head ----
  final_kernel<<<1, 128, 0, stream>>>(pooled, lin_w, lin_b, out);
}

// Round 17
// 455.389 us; speedup vs baseline: 1.0941x; 1.0503x over previous
//
#include <hip/hip_runtime.h>
#include <hip/hip_bf16.h>

#define N_NODES 200000
#define N_EDGES 400000
#define HID 128

#define SHIFT 10                       // 1024 segments per bucket
#define NB_E 391                       // ceil(400000/1024)
#define NB_V 196                       // ceil(200000/1024)
#define NBT (NB_E + NB_V)              // 587
#define CAP_E 6144                     // fixed slab capacity per e-bucket
#define CAP_V 10240                    // fixed slab capacity per v-bucket
#define BINSZ 4096                     // entries per bin block

typedef unsigned int u32;
typedef unsigned short u16;
typedef unsigned char u8;
typedef long long i64;
typedef __attribute__((ext_vector_type(4))) float f32x4;
typedef __attribute__((ext_vector_type(2))) float f32x2;

__device__ inline float sigmoidf(float v) { return 1.0f / (1.0f + __expf(-v)); }

// pack 4 f32 -> 4 fp8 (e4m3) in one u32
__device__ inline u32 pk4_fp8(float f0, float f1, float f2, float f3) {
  u32 v = __builtin_amdgcn_cvt_pk_fp8_f32(f0, f1, 0, false);
  v = __builtin_amdgcn_cvt_pk_fp8_f32(f2, f3, v, true);
  return v;
}

// accumulate 16 fp8 channels (one uint4) with weight wv into 8 f32x2 accs
__device__ inline void acc16_fp8(const uint4& q, float wv, f32x2* a) {
#pragma unroll
  for (int h = 0; h < 4; ++h) {
    u32 u = (&q.x)[h];
    a[h * 2 + 0] += __builtin_amdgcn_cvt_pk_f32_fp8(u, false) * wv;
    a[h * 2 + 1] += __builtin_amdgcn_cvt_pk_f32_fp8(u, true) * wv;
  }
}

// ---- bin (+ fused independent mm14) — R14-proven structure --------------------
__global__ __launch_bounds__(256) void bin_mm14_kernel(
    const int* __restrict__ rows, const int* __restrict__ cols,
    const float* __restrict__ vals, u32* __restrict__ bkE,
    u32* __restrict__ bkV, int2* __restrict__ tmp_e, int2* __restrict__ tmp_v,
    int nnz, int nbBin, const float* __restrict__ x0,
    const float* __restrict__ w14, u8* __restrict__ U, int N) {
  __shared__ u32 smem[14 * HID];   // 7168 B: ws (mm14) or h+base (bin)
  const int tid = threadIdx.x;

  if ((int)blockIdx.x >= nbBin) {
    // ---- mm14 role ----
    float* ws = (float*)smem;
    for (int i = tid; i < 14 * HID; i += 256) ws[i] = w14[i];
    __syncthreads();
    const int row = ((int)blockIdx.x - nbBin) * 8 + (tid >> 5);
    const int c4 = (tid & 31) << 2;
    if (row >= N) return;
    const float* xr = x0 + (size_t)row * 14;
    float a0 = 0.f, a1 = 0.f, a2 = 0.f, a3 = 0.f;
#pragma unroll
    for (int k = 0; k < 14; ++k) {
      const float xv = xr[k];
      const float* wr = ws + k * HID + c4;
      a0 = fmaf(xv, wr[0], a0);
      a1 = fmaf(xv, wr[1], a1);
      a2 = fmaf(xv, wr[2], a2);
      a3 = fmaf(xv, wr[3], a3);
    }
    *(u32*)(U + (size_t)row * HID + c4) = pk4_fp8(a0, a1, a2, a3);
    return;
  }

  // ---- bin role ----
  u32* h = smem;
  u32* base = smem + NBT;
  for (int j = tid; j < NBT; j += 256) h[j] = 0;
  __syncthreads();
  const int i0 = blockIdx.x * BINSZ;
  for (int k = 0; k < BINSZ / 256; ++k) {
    int i = i0 + k * 256 + tid;
    if (i < nnz) {
      atomicAdd(&h[cols[i] >> SHIFT], 1u);
      atomicAdd(&h[NB_E + (rows[i] >> SHIFT)], 1u);
    }
  }
  __syncthreads();
  for (int j = tid; j < NBT; j += 256) {
    u32 n = h[j];
    base[j] = n ? ((j < NB_E) ? atomicAdd(&bkE[j], n)
                              : atomicAdd(&bkV[j - NB_E], n))
                : 0;
    h[j] = 0;
  }
  __syncthreads();
  for (int k = 0; k < BINSZ / 256; ++k) {
    int i = i0 + k * 256 + tid;
    if (i < nnz) {
      int c = cols[i], r = rows[i];
      int vb = __float_as_int(vals[i]);
      int be = c >> SHIFT;
      int bv = NB_E + (r >> SHIFT);
      u32 le = atomicAdd(&h[be], 1u);
      tmp_e[(size_t)be * CAP_E + base[be] + le] =
          make_int2(((c & 1023) << 19) | r, vb);
      u32 lv = atomicAdd(&h[bv], 1u);
      tmp_v[(size_t)(bv - NB_E) * CAP_V + base[bv] + lv] =
          make_int2(((r & 1023) << 19) | c, vb);
    }
  }
}

// merged: block0 scans bkE, block1 scans bkV, block2 sentinels + pooled zero.
__global__ __launch_bounds__(512) void scan_all_kernel(
    u32* __restrict__ bkE, u32* __restrict__ bkV, u32* __restrict__ ptr_e,
    u32* __restrict__ ptr_v, u32* __restrict__ pooled, u32 nnz) {
  if (blockIdx.x == 2) {
    if (threadIdx.x < HID) pooled[threadIdx.x] = 0;
    if (threadIdx.x == 0) {
      bkE[NB_E] = nnz;
      bkV[NB_V] = nnz;
      ptr_e[N_EDGES] = nnz;
      ptr_v[N_NODES] = nnz;
    }
    return;
  }
  u32* blk = (blockIdx.x == 0) ? bkE : bkV;
  const int n = (blockIdx.x == 0) ? NB_E : NB_V;
  __shared__ u32 tmp[512];
  int t = threadIdx.x;
  u32 v = (t < n) ? blk[t] : 0;
  tmp[t] = v;
  __syncthreads();
  for (int d = 1; d < 512; d <<= 1) {
    u32 x = (t >= d) ? tmp[t - d] : 0;
    __syncthreads();
    tmp[t] += x;
    __syncthreads();
  }
  if (t < n) blk[t] = tmp[t] - v;
}

// Per bucket: LDS count + scan -> ptr, place entries from the bucket slab
// (L2-local), compute cards; EDGE side also computes denom + final weights.
template <bool EDGE>
__global__ __launch_bounds__(512) void build_kernel(
    const int2* __restrict__ tmp, int cap, const u32* __restrict__ bukBase,
    u32* __restrict__ ptr, int2* __restrict__ ent, float* __restrict__ card,
    const float* __restrict__ ncard, int S) {
  __shared__ u32 loc[1024];
  __shared__ u32 sstart[1024];
  __shared__ u32 aux[512];
  const int tid = threadIdx.x;
  const int c0 = blockIdx.x << SHIFT;
  const int nseg = min(1024, S - c0);
  const u32 eb = bukBase[blockIdx.x], ee = bukBase[blockIdx.x + 1];
  const u32 cnt = ee - eb;
  const int2* tp = tmp + (size_t)blockIdx.x * cap;
  loc[tid] = 0;
  loc[tid + 512] = 0;
  __syncthreads();
  for (u32 j = tid; j < cnt; j += 512)
    atomicAdd(&loc[(u32)tp[j].x >> 19], 1u);
  __syncthreads();
  u32 a0 = loc[2 * tid], a1 = loc[2 * tid + 1];
  u32 T = a0 + a1;
  aux[tid] = T;
  __syncthreads();
  for (int d = 1; d < 512; d <<= 1) {
    u32 x = (tid >= d) ? aux[tid - d] : 0;
    __syncthreads();
    aux[tid] += x;
    __syncthreads();
  }
  u32 off = aux[tid] - T;
  loc[2 * tid] = off;
  loc[2 * tid + 1] = off + a0;
  sstart[2 * tid] = off;
  sstart[2 * tid + 1] = off + a0;
  __syncthreads();
  for (int k = tid; k < nseg; k += 512) ptr[c0 + k] = eb + loc[k];
  __syncthreads();
  for (u32 j = tid; j < cnt; j += 512) {
    int2 e = tp[j];
    u32 s = (u32)e.x >> 19;
    u32 p = atomicAdd(&loc[s], 1u);
    ent[eb + p] = make_int2(e.x & 0x7FFFF, e.y);   // {idx, raw val}
  }
  __syncthreads();
  for (int k = tid; k < nseg; k += 512) {
    u32 s0 = eb + sstart[k], s1 = eb + loc[k];
    float s = 0.f;
    for (u32 j = s0; j < s1; ++j) s += __int_as_float(ent[j].y);
    float t = rsqrtf(s);
    card[c0 + k] = EDGE ? t * t * t : t;   // deg^-1.5 : deg^-0.5
    if (EDGE) {
      float d = 0.f;
      for (u32 j = s0; j < s1; ++j) {
        int2 en = ent[j];
        d += __int_as_float(en.y) * ncard[en.x];
      }
      float inv = 1.f / d;
      for (u32 j = s0; j < s1; ++j) {
        int2 en = ent[j];
        ent[j].y = __float_as_int(__int_as_float(en.y) * ncard[en.x] * inv);
      }
    }
  }
}

// v-side weights, 2 lanes per segment (shfl-combined denom).
__global__ __launch_bounds__(256) void segV_kernel(
    const u32* __restrict__ ptr_v, int2* __restrict__ ent_v,
    const float* __restrict__ e_card) {
  int t = blockIdx.x * 256 + threadIdx.x;
  int i = t >> 1;
  int half = t & 1;
  if (i >= N_NODES) return;
  u32 b = ptr_v[i], e = ptr_v[i + 1];
  float s = 0.f;
  for (u32 j = b + half; j < e; j += 2) {
    int2 en = ent_v[j];
    s += __int_as_float(en.y) * e_card[en.x];
  }
  s += __shfl_xor(s, 1);
  float inv = 1.f / s;
  for (u32 j = b + half; j < e; j += 2) {
    int2 en = ent_v[j];
    ent_v[j].y = __float_as_int(__int_as_float(en.y) * e_card[en.x] * inv);
  }
}

// ---- dense matmuls ----------------------------------------------------------

// load one 128x128 weight matrix as per-wave fp8 B-fragments
__device__ inline void load_wfrags(const float* __restrict__ w, int lo, int hi,
                                   i64 wf[8][4]) {
#pragma unroll
  for (int n = 0; n < 8; ++n)
#pragma unroll
    for (int t = 0; t < 4; ++t) {
      const float* wp = w + (size_t)(t * 32 + hi * 8) * HID + n * 16 + lo;
      u32 w0 = pk4_fp8(wp[0], wp[HID], wp[2 * HID], wp[3 * HID]);
      u32 w1 = pk4_fp8(wp[4 * HID], wp[5 * HID], wp[6 * HID], wp[7 * HID]);
      wf[n][t] = (i64)w0 | ((i64)w1 << 32);
    }
}

// buf[R,128] = [sigmoid](buf @ w [+ b]) in-place, fp8 MFMA; optional max-pool.
template <bool SIG, bool POOL>
__global__ __launch_bounds__(256, 1) void im128_mfma_kernel(
    u8* __restrict__ buf, const float* __restrict__ w,
    const float* __restrict__ b, u32* __restrict__ pooled, int R) {
  const int tid = threadIdx.x;
  const int wave = tid >> 6;
  const int lo = tid & 15;
  const int hi = (tid & 63) >> 4;
  i64 wf[8][4];
  load_wfrags(w, lo, hi, wf);
  float bias[8];
  if (SIG) {
#pragma unroll
    for (int n = 0; n < 8; ++n) bias[n] = b[n * 16 + lo];
  }
  float pm[8];
#pragma unroll
  for (int n = 0; n < 8; ++n) pm[n] = 0.f;

  for (int rb = blockIdx.x * 64 + wave * 16; rb < R; rb += gridDim.x * 64) {
    const u8* xp = buf + (size_t)(rb + lo) * HID + hi * 8;
    i64 a0 = *(const i64*)(xp);
    i64 a1 = *(const i64*)(xp + 32);
    i64 a2 = *(const i64*)(xp + 64);
    i64 a3 = *(const i64*)(xp + 96);
    u8* yp = buf + (size_t)(rb + hi * 4) * HID + lo;
#pragma unroll
    for (int n = 0; n < 8; ++n) {
      f32x4 c = {0.f, 0.f, 0.f, 0.f};
      c = __builtin_amdgcn_mfma_f32_16x16x32_fp8_fp8(a0, wf[n][0], c, 0, 0, 0);
      c = __builtin_amdgcn_mfma_f32_16x16x32_fp8_fp8(a1, wf[n][1], c, 0, 0, 0);
      c = __builtin_amdgcn_mfma_f32_16x16x32_fp8_fp8(a2, wf[n][2], c, 0, 0, 0);
      c = __builtin_amdgcn_mfma_f32_16x16x32_fp8_fp8(a3, wf[n][3], c, 0, 0, 0);
#pragma unroll
      for (int r = 0; r < 4; ++r) {
        float v = SIG ? sigmoidf(c[r] + bias[n]) : c[r];
        if (POOL) {
          pm[n] = fmaxf(pm[n], v);
        } else {
          u32 q = __builtin_amdgcn_cvt_pk_fp8_f32(v, v, 0, false);
          yp[(size_t)r * HID + n * 16] = (u8)q;
        }
      }
    }
  }

  if (POOL) {
    __shared__ u32 pmax[HID];
    for (int i = tid; i < HID; i += 256) pmax[i] = 0;
    __syncthreads();
#pragma unroll
    for (int n = 0; n < 8; ++n)
      atomicMax(&pmax[n * 16 + lo], __float_as_uint(pm[n]));
    __syncthreads();
    if (tid < HID) atomicMax(&pooled[tid], pmax[tid]);
  }
}

// ---- gathers ----------------------------------------------------------------

// dst[r][:] = [sigmoid](sum_j w[j] * src[idx[j]][:] [+ b]), fp8 in/out.
// 8 threads/row x 16 channels; 4-deep unroll (4 independent src loads in
// flight), remainder 2-then-1. Per-accumulator order unchanged (bitwise-same).
template <bool SIG>
__global__ __launch_bounds__(256) void gather128_kernel(
    const u32* __restrict__ ptr, const int2* __restrict__ ent,
    const u8* __restrict__ src, const float* __restrict__ b,
    u8* __restrict__ dst, int S) {
  long long t = (long long)blockIdx.x * 256 + threadIdx.x;
  int r = (int)(t >> 3);
  if (r >= S) return;
  const int c16 = (int)(t & 7) << 4;  // 16 channels (16 bytes)
  u32 beg = ptr[r], end = ptr[r + 1];
  f32x2 a[8];
#pragma unroll
  for (int i = 0; i < 8; ++i) a[i] = (f32x2){0.f, 0.f};
  u32 j = beg;
  for (; j + 4 <= end; j += 4) {
    int2 e0 = ent[j];
    int2 e1 = ent[j + 1];
    int2 e2 = ent[j + 2];
    int2 e3 = ent[j + 3];
    const uint4 q0 = *(const uint4*)(src + (size_t)e0.x * HID + c16);
    const uint4 q1 = *(const uint4*)(src + (size_t)e1.x * HID + c16);
    const uint4 q2 = *(const uint4*)(src + (size_t)e2.x * HID + c16);
    const uint4 q3 = *(const uint4*)(src + (size_t)e3.x * HID + c16);
    acc16_fp8(q0, __int_as_float(e0.y), a);
    acc16_fp8(q1, __int_as_float(e1.y), a);
    acc16_fp8(q2, __int_as_float(e2.y), a);
    acc16_fp8(q3, __int_as_float(e3.y), a);
  }
  if (j + 2 <= end) {
    int2 e0 = ent[j];
    int2 e1 = ent[j + 1];
    const uint4 q0 = *(const uint4*)(src + (size_t)e0.x * HID + c16);
    const uint4 q1 = *(const uint4*)(src + (size_t)e1.x * HID + c16);
    acc16_fp8(q0, __int_as_float(e0.y), a);
    acc16_fp8(q1, __int_as_float(e1.y), a);
    j += 2;
  }
  if (j < end) {
    int2 e0 = ent[j];
    const uint4 q0 = *(const uint4*)(src + (size_t)e0.x * HID + c16);
    acc16_fp8(q0, __int_as_float(e0.y), a);
  }
  float o[16];
#pragma unroll
  for (int h = 0; h < 4; ++h) {
    o[h * 4 + 0] = a[h * 2 + 0].x;
    o[h * 4 + 1] = a[h * 2 + 0].y;
    o[h * 4 + 2] = a[h * 2 + 1].x;
    o[h * 4 + 3] = a[h * 2 + 1].y;
  }
  if (SIG) {
#pragma unroll
    for (int h = 0; h < 4; ++h) {
      float4 bb = *(const float4*)(b + c16 + h * 4);
      o[h * 4 + 0] = sigmoidf(o[h * 4 + 0] + bb.x);
      o[h * 4 + 1] = sigmoidf(o[h * 4 + 1] + bb.y);
      o[h * 4 + 2] = sigmoidf(o[h * 4 + 2] + bb.z);
      o[h * 4 + 3] = sigmoidf(o[h * 4 + 3] + bb.w);
    }
  }
  uint4 pk;
  pk.x = pk4_fp8(o[0], o[1], o[2], o[3]);
  pk.y = pk4_fp8(o[4], o[5], o[6], o[7]);
  pk.z = pk4_fp8(o[8], o[9], o[10], o[11]);
  pk.w = pk4_fp8(o[12], o[13], o[14], o[15]);
  *(uint4*)(dst + (size_t)r * HID + c16) = pk;
}

// ---- head ---------------------------------------------------------------

__global__ __launch_bounds__(128) void final_kernel(
    const u32* __restrict__ pooled, const float* __restrict__ lin_w,
    const float* __restrict__ lin_b, float* __restrict__ out) {
  __shared__ float red[64];
  int t = threadIdx.x;
  float v = __uint_as_float(pooled[t]) * lin_w[t];
  if (t >= 64) red[t - 64] = v;
  __syncthreads();
  if (t < 64) {
    v += red[t];
#pragma unroll
    for (int off = 32; off > 0; off >>= 1) v += __shfl_down(v, off);
    if (t == 0) out[0] = v + lin_b[0];
  }
}

__global__ void diag_kernel(float* out, float v) { out[0] = v; }

// ---- launch -----------------------------------------------------------------

extern "C" void kernel_launch(void* const* d_in, const int* in_sizes, int n_in,
                              void* d_out, int out_size, void* d_ws, size_t ws_size,
                              hipStream_t stream) {
  const float* x0     = (const float*)d_in[0];
  const int*   rows   = (const int*)d_in[1];
  const int*   cols   = (const int*)d_in[2];
  const float* vals   = (const float*)d_in[3];
  const float* w0_l1  = (const float*)d_in[4];
  const float* w1_l1  = (const float*)d_in[5];
  const float* b1_l1  = (const float*)d_in[6];
  const float* b0_l1  = (const float*)d_in[7];
  const float* w0_l2  = (const float*)d_in[8];
  const float* w1_l2  = (const float*)d_in[9];
  const float* b1_l2  = (const float*)d_in[10];
  const float* b0_l2  = (const float*)d_in[11];
  const float* lin_w  = (const float*)d_in[12];
  const float* lin_b  = (const float*)d_in[13];
  float* out = (float*)d_out;
  const int nnz = in_sizes[1];

  char* wsp = (char*)d_ws;
  size_t off = 0;
  auto carve = [&](size_t bytes) -> char* {
    char* p = wsp + off;
    off = (off + bytes + 511) & ~(size_t)511;
    return p;
  };
  float* n_card  = (float*)carve((size_t)N_NODES * 4);
  float* e_card  = (float*)carve((size_t)N_EDGES * 4);
  u32*   ptr_v   = (u32*)carve((size_t)(N_NODES + 1) * 4);
  u32*   ptr_e   = (u32*)carve((size_t)(N_EDGES + 1) * 4);
  u32*   bkE     = (u32*)carve((NB_E + 1) * 4);   // counts -> bases (adjacent:
  u32*   bkV     = (u32*)carve((NB_V + 1) * 4);   //  one memset covers both)
  int2*  ent_v   = (int2*)carve((size_t)nnz * 8);   // {idx, val->weight}
  int2*  ent_e   = (int2*)carve((size_t)nnz * 8);
  u32*   pooled  = (u32*)carve(HID * 4);
  u8*    bufN    = (u8*)carve((size_t)N_NODES * HID);        // 25.6 MB fp8
  u8*    bufE    = (u8*)carve((size_t)N_EDGES * HID);        // 51.2 MB fp8
  int2*  tmp_e   = (int2*)carve((size_t)NB_E * CAP_E * 8);   // 19.2 MB slabs
  int2*  tmp_v   = (int2*)carve((size_t)NB_V * CAP_V * 8);   // 16.1 MB slabs

  if (off > ws_size) {  // diagnostic: report ws MB via absmax instead of crashing
    diag_kernel<<<1, 1, 0, stream>>>(out, (float)(ws_size >> 20));
    return;
  }

  // single memset spanning bkE..bkV (adjacent carves incl. 512B padding)
  hipMemsetAsync(bkE, 0, (size_t)((char*)ent_v - (char*)bkE), stream);

  const int nbBin = (nnz + BINSZ - 1) / BINSZ;
  const int nbMM14 = (N_NODES + 7) / 8;

  // CSR build (+ mm14 backfill) -> scans -> build -> segV
  bin_mm14_kernel<<<nbBin + nbMM14, 256, 0, stream>>>(
      rows, cols, vals, bkE, bkV, tmp_e, tmp_v, nnz, nbBin,
      x0, w0_l1, bufN, N_NODES);
  scan_all_kernel<<<3, 512, 0, stream>>>(bkE, bkV, ptr_e, ptr_v, pooled, (u32)nnz);
  build_kernel<false><<<NB_V, 512, 0, stream>>>(tmp_v, CAP_V, bkV, ptr_v,
                                                ent_v, n_card, nullptr, N_NODES);
  build_kernel<true><<<NB_E, 512, 0, stream>>>(tmp_e, CAP_E, bkE, ptr_e,
                                               ent_e, e_card, n_card, N_EDGES);
  segV_kernel<<<(2 * N_NODES + 255) / 256, 256, 0, stream>>>(ptr_v, ent_v, e_card);

  const int nbE8 = (int)(((long long)N_EDGES * 8 + 255) / 256);
  const int nbN8 = (int)(((long long)N_NODES * 8 + 255) / 256);

  // ---- layer 1 ----
  gather128_kernel<true><<<nbE8, 256, 0, stream>>>(ptr_e, ent_e, bufN,
                                                   b1_l1, bufE, N_EDGES);
  gather128_kernel<false><<<nbN8, 256, 0, stream>>>(ptr_v, ent_v, bufE,
                                                    nullptr, bufN, N_NODES);
  im128_mfma_kernel<true, false><<<1024, 256, 0, stream>>>(bufN, w1_l1, b0_l1,
                                                           nullptr, N_NODES);

  // ---- layer 2 ----
  im128_mfma_kernel<false, false><<<1024, 256, 0, stream>>>(bufN, w0_l2, nullptr,
                                                            nullptr, N_NODES);
  gather128_kernel<true><<<nbE8, 256, 0, stream>>>(ptr_e, ent_e, bufN,
                                                   b1_l2, bufE, N_EDGES);
  gather128_kernel<false><<<nbN8, 256, 0, stream>>>(ptr_v, ent_v, bufE,
                                                    nullptr, bufN, N_NODES);
  im128_mfma_kernel<true, true><<<1024, 256, 0, stream>>>(bufN, w1_l2, b0_l2,
                                                          pooled, N_NODES);

  // ---- head ----
  final_kernel<<<1, 128, 0, stream>>>(pooled, lin_w, lin_b, out);
}

// Round 18
// 446.188 us; speedup vs baseline: 1.1166x; 1.0206x over previous
//
#include <hip/hip_runtime.h>
#include <hip/hip_bf16.h>

#define N_NODES 200000
#define N_EDGES 400000
#define HID 128

#define SHIFT 10                       // 1024 segments per bucket
#define NB_E 391                       // ceil(400000/1024)
#define NB_V 196                       // ceil(200000/1024)
#define NBT (NB_E + NB_V)              // 587
#define CAP_E 6144                     // fixed slab capacity per e-bucket
#define CAP_V 10240                    // fixed slab capacity per v-bucket
#define BINSZ 4096                     // entries per bin block

typedef unsigned int u32;
typedef unsigned short u16;
typedef unsigned char u8;
typedef long long i64;
typedef __attribute__((ext_vector_type(4))) float f32x4;
typedef __attribute__((ext_vector_type(2))) float f32x2;

__device__ inline float sigmoidf(float v) { return 1.0f / (1.0f + __expf(-v)); }

// pack 4 f32 -> 4 fp8 (e4m3) in one u32
__device__ inline u32 pk4_fp8(float f0, float f1, float f2, float f3) {
  u32 v = __builtin_amdgcn_cvt_pk_fp8_f32(f0, f1, 0, false);
  v = __builtin_amdgcn_cvt_pk_fp8_f32(f2, f3, v, true);
  return v;
}

// accumulate 16 fp8 channels (one uint4) with weight wv into 8 f32x2 accs
__device__ inline void acc16_fp8(const uint4& q, float wv, f32x2* a) {
#pragma unroll
  for (int h = 0; h < 4; ++h) {
    u32 u = (&q.x)[h];
    a[h * 2 + 0] += __builtin_amdgcn_cvt_pk_f32_fp8(u, false) * wv;
    a[h * 2 + 1] += __builtin_amdgcn_cvt_pk_f32_fp8(u, true) * wv;
  }
}

// ---- bin (+ fused independent mm14) — R14-proven structure --------------------
__global__ __launch_bounds__(256) void bin_mm14_kernel(
    const int* __restrict__ rows, const int* __restrict__ cols,
    const float* __restrict__ vals, u32* __restrict__ bkE,
    u32* __restrict__ bkV, int2* __restrict__ tmp_e, int2* __restrict__ tmp_v,
    int nnz, int nbBin, const float* __restrict__ x0,
    const float* __restrict__ w14, u8* __restrict__ U, int N) {
  __shared__ u32 smem[14 * HID];   // 7168 B: ws (mm14) or h+base (bin)
  const int tid = threadIdx.x;

  if ((int)blockIdx.x >= nbBin) {
    // ---- mm14 role ----
    float* ws = (float*)smem;
    for (int i = tid; i < 14 * HID; i += 256) ws[i] = w14[i];
    __syncthreads();
    const int row = ((int)blockIdx.x - nbBin) * 8 + (tid >> 5);
    const int c4 = (tid & 31) << 2;
    if (row >= N) return;
    const float* xr = x0 + (size_t)row * 14;
    float a0 = 0.f, a1 = 0.f, a2 = 0.f, a3 = 0.f;
#pragma unroll
    for (int k = 0; k < 14; ++k) {
      const float xv = xr[k];
      const float* wr = ws + k * HID + c4;
      a0 = fmaf(xv, wr[0], a0);
      a1 = fmaf(xv, wr[1], a1);
      a2 = fmaf(xv, wr[2], a2);
      a3 = fmaf(xv, wr[3], a3);
    }
    *(u32*)(U + (size_t)row * HID + c4) = pk4_fp8(a0, a1, a2, a3);
    return;
  }

  // ---- bin role ----
  u32* h = smem;
  u32* base = smem + NBT;
  for (int j = tid; j < NBT; j += 256) h[j] = 0;
  __syncthreads();
  const int i0 = blockIdx.x * BINSZ;
  for (int k = 0; k < BINSZ / 256; ++k) {
    int i = i0 + k * 256 + tid;
    if (i < nnz) {
      atomicAdd(&h[cols[i] >> SHIFT], 1u);
      atomicAdd(&h[NB_E + (rows[i] >> SHIFT)], 1u);
    }
  }
  __syncthreads();
  for (int j = tid; j < NBT; j += 256) {
    u32 n = h[j];
    base[j] = n ? ((j < NB_E) ? atomicAdd(&bkE[j], n)
                              : atomicAdd(&bkV[j - NB_E], n))
                : 0;
    h[j] = 0;
  }
  __syncthreads();
  for (int k = 0; k < BINSZ / 256; ++k) {
    int i = i0 + k * 256 + tid;
    if (i < nnz) {
      int c = cols[i], r = rows[i];
      int vb = __float_as_int(vals[i]);
      int be = c >> SHIFT;
      int bv = NB_E + (r >> SHIFT);
      u32 le = atomicAdd(&h[be], 1u);
      tmp_e[(size_t)be * CAP_E + base[be] + le] =
          make_int2(((c & 1023) << 19) | r, vb);
      u32 lv = atomicAdd(&h[bv], 1u);
      tmp_v[(size_t)(bv - NB_E) * CAP_V + base[bv] + lv] =
          make_int2(((r & 1023) << 19) | c, vb);
    }
  }
}

// merged: block0 scans bkE, block1 scans bkV, block2 sentinels + pooled zero.
__global__ __launch_bounds__(512) void scan_all_kernel(
    u32* __restrict__ bkE, u32* __restrict__ bkV, u32* __restrict__ ptr_e,
    u32* __restrict__ ptr_v, u32* __restrict__ pooled, u32 nnz) {
  if (blockIdx.x == 2) {
    if (threadIdx.x < HID) pooled[threadIdx.x] = 0;
    if (threadIdx.x == 0) {
      bkE[NB_E] = nnz;
      bkV[NB_V] = nnz;
      ptr_e[N_EDGES] = nnz;
      ptr_v[N_NODES] = nnz;
    }
    return;
  }
  u32* blk = (blockIdx.x == 0) ? bkE : bkV;
  const int n = (blockIdx.x == 0) ? NB_E : NB_V;
  __shared__ u32 tmp[512];
  int t = threadIdx.x;
  u32 v = (t < n) ? blk[t] : 0;
  tmp[t] = v;
  __syncthreads();
  for (int d = 1; d < 512; d <<= 1) {
    u32 x = (t >= d) ? tmp[t - d] : 0;
    __syncthreads();
    tmp[t] += x;
    __syncthreads();
  }
  if (t < n) blk[t] = tmp[t] - v;
}

// Per bucket: LDS count + scan -> ptr, place entries from the bucket slab
// (L2-local), compute cards; EDGE side also computes denom + final weights.
template <bool EDGE>
__global__ __launch_bounds__(512) void build_kernel(
    const int2* __restrict__ tmp, int cap, const u32* __restrict__ bukBase,
    u32* __restrict__ ptr, int2* __restrict__ ent, float* __restrict__ card,
    const float* __restrict__ ncard, int S) {
  __shared__ u32 loc[1024];
  __shared__ u32 sstart[1024];
  __shared__ u32 aux[512];
  const int tid = threadIdx.x;
  const int c0 = blockIdx.x << SHIFT;
  const int nseg = min(1024, S - c0);
  const u32 eb = bukBase[blockIdx.x], ee = bukBase[blockIdx.x + 1];
  const u32 cnt = ee - eb;
  const int2* tp = tmp + (size_t)blockIdx.x * cap;
  loc[tid] = 0;
  loc[tid + 512] = 0;
  __syncthreads();
  for (u32 j = tid; j < cnt; j += 512)
    atomicAdd(&loc[(u32)tp[j].x >> 19], 1u);
  __syncthreads();
  u32 a0 = loc[2 * tid], a1 = loc[2 * tid + 1];
  u32 T = a0 + a1;
  aux[tid] = T;
  __syncthreads();
  for (int d = 1; d < 512; d <<= 1) {
    u32 x = (tid >= d) ? aux[tid - d] : 0;
    __syncthreads();
    aux[tid] += x;
    __syncthreads();
  }
  u32 off = aux[tid] - T;
  loc[2 * tid] = off;
  loc[2 * tid + 1] = off + a0;
  sstart[2 * tid] = off;
  sstart[2 * tid + 1] = off + a0;
  __syncthreads();
  for (int k = tid; k < nseg; k += 512) ptr[c0 + k] = eb + loc[k];
  __syncthreads();
  for (u32 j = tid; j < cnt; j += 512) {
    int2 e = tp[j];
    u32 s = (u32)e.x >> 19;
    u32 p = atomicAdd(&loc[s], 1u);
    ent[eb + p] = make_int2(e.x & 0x7FFFF, e.y);   // {idx, raw val}
  }
  __syncthreads();
  for (int k = tid; k < nseg; k += 512) {
    u32 s0 = eb + sstart[k], s1 = eb + loc[k];
    float s = 0.f;
    for (u32 j = s0; j < s1; ++j) s += __int_as_float(ent[j].y);
    float t = rsqrtf(s);
    card[c0 + k] = EDGE ? t * t * t : t;   // deg^-1.5 : deg^-0.5
    if (EDGE) {
      float d = 0.f;
      for (u32 j = s0; j < s1; ++j) {
        int2 en = ent[j];
        d += __int_as_float(en.y) * ncard[en.x];
      }
      float inv = 1.f / d;
      for (u32 j = s0; j < s1; ++j) {
        int2 en = ent[j];
        ent[j].y = __float_as_int(__int_as_float(en.y) * ncard[en.x] * inv);
      }
    }
  }
}

// ---- dense matmuls ----------------------------------------------------------

// load one 128x128 weight matrix as per-wave fp8 B-fragments
__device__ inline void load_wfrags(const float* __restrict__ w, int lo, int hi,
                                   i64 wf[8][4]) {
#pragma unroll
  for (int n = 0; n < 8; ++n)
#pragma unroll
    for (int t = 0; t < 4; ++t) {
      const float* wp = w + (size_t)(t * 32 + hi * 8) * HID + n * 16 + lo;
      u32 w0 = pk4_fp8(wp[0], wp[HID], wp[2 * HID], wp[3 * HID]);
      u32 w1 = pk4_fp8(wp[4 * HID], wp[5 * HID], wp[6 * HID], wp[7 * HID]);
      wf[n][t] = (i64)w0 | ((i64)w1 << 32);
    }
}

// buf[R,128] = [sigmoid](buf @ w [+ b]) in-place, fp8 MFMA; optional max-pool.
template <bool SIG, bool POOL>
__global__ __launch_bounds__(256, 1) void im128_mfma_kernel(
    u8* __restrict__ buf, const float* __restrict__ w,
    const float* __restrict__ b, u32* __restrict__ pooled, int R) {
  const int tid = threadIdx.x;
  const int wave = tid >> 6;
  const int lo = tid & 15;
  const int hi = (tid & 63) >> 4;
  i64 wf[8][4];
  load_wfrags(w, lo, hi, wf);
  float bias[8];
  if (SIG) {
#pragma unroll
    for (int n = 0; n < 8; ++n) bias[n] = b[n * 16 + lo];
  }
  float pm[8];
#pragma unroll
  for (int n = 0; n < 8; ++n) pm[n] = 0.f;

  for (int rb = blockIdx.x * 64 + wave * 16; rb < R; rb += gridDim.x * 64) {
    const u8* xp = buf + (size_t)(rb + lo) * HID + hi * 8;
    i64 a0 = *(const i64*)(xp);
    i64 a1 = *(const i64*)(xp + 32);
    i64 a2 = *(const i64*)(xp + 64);
    i64 a3 = *(const i64*)(xp + 96);
    u8* yp = buf + (size_t)(rb + hi * 4) * HID + lo;
#pragma unroll
    for (int n = 0; n < 8; ++n) {
      f32x4 c = {0.f, 0.f, 0.f, 0.f};
      c = __builtin_amdgcn_mfma_f32_16x16x32_fp8_fp8(a0, wf[n][0], c, 0, 0, 0);
      c = __builtin_amdgcn_mfma_f32_16x16x32_fp8_fp8(a1, wf[n][1], c, 0, 0, 0);
      c = __builtin_amdgcn_mfma_f32_16x16x32_fp8_fp8(a2, wf[n][2], c, 0, 0, 0);
      c = __builtin_amdgcn_mfma_f32_16x16x32_fp8_fp8(a3, wf[n][3], c, 0, 0, 0);
#pragma unroll
      for (int r = 0; r < 4; ++r) {
        float v = SIG ? sigmoidf(c[r] + bias[n]) : c[r];
        if (POOL) {
          pm[n] = fmaxf(pm[n], v);
        } else {
          u32 q = __builtin_amdgcn_cvt_pk_fp8_f32(v, v, 0, false);
          yp[(size_t)r * HID + n * 16] = (u8)q;
        }
      }
    }
  }

  if (POOL) {
    __shared__ u32 pmax[HID];
    for (int i = tid; i < HID; i += 256) pmax[i] = 0;
    __syncthreads();
#pragma unroll
    for (int n = 0; n < 8; ++n)
      atomicMax(&pmax[n * 16 + lo], __float_as_uint(pm[n]));
    __syncthreads();
    if (tid < HID) atomicMax(&pooled[tid], pmax[tid]);
  }
}

// ---- gathers ----------------------------------------------------------------

// gather body: dst[r][:] = [sigmoid](sum_j w[j]*src[idx[j]][:] [+b]), fp8.
template <bool SIG>
__device__ inline void gather_body(long long t, const u32* __restrict__ ptr,
                                   const int2* __restrict__ ent,
                                   const u8* __restrict__ src,
                                   const float* __restrict__ b,
                                   u8* __restrict__ dst, int S) {
  int r = (int)(t >> 3);
  if (r >= S) return;
  const int c16 = (int)(t & 7) << 4;  // 16 channels (16 bytes)
  u32 beg = ptr[r], end = ptr[r + 1];
  f32x2 a[8];
#pragma unroll
  for (int i = 0; i < 8; ++i) a[i] = (f32x2){0.f, 0.f};
  u32 j = beg;
  for (; j + 4 <= end; j += 4) {
    int2 e0 = ent[j];
    int2 e1 = ent[j + 1];
    int2 e2 = ent[j + 2];
    int2 e3 = ent[j + 3];
    const uint4 q0 = *(const uint4*)(src + (size_t)e0.x * HID + c16);
    const uint4 q1 = *(const uint4*)(src + (size_t)e1.x * HID + c16);
    const uint4 q2 = *(const uint4*)(src + (size_t)e2.x * HID + c16);
    const uint4 q3 = *(const uint4*)(src + (size_t)e3.x * HID + c16);
    acc16_fp8(q0, __int_as_float(e0.y), a);
    acc16_fp8(q1, __int_as_float(e1.y), a);
    acc16_fp8(q2, __int_as_float(e2.y), a);
    acc16_fp8(q3, __int_as_float(e3.y), a);
  }
  if (j + 2 <= end) {
    int2 e0 = ent[j];
    int2 e1 = ent[j + 1];
    const uint4 q0 = *(const uint4*)(src + (size_t)e0.x * HID + c16);
    const uint4 q1 = *(const uint4*)(src + (size_t)e1.x * HID + c16);
    acc16_fp8(q0, __int_as_float(e0.y), a);
    acc16_fp8(q1, __int_as_float(e1.y), a);
    j += 2;
  }
  if (j < end) {
    int2 e0 = ent[j];
    const uint4 q0 = *(const uint4*)(src + (size_t)e0.x * HID + c16);
    acc16_fp8(q0, __int_as_float(e0.y), a);
  }
  float o[16];
#pragma unroll
  for (int h = 0; h < 4; ++h) {
    o[h * 4 + 0] = a[h * 2 + 0].x;
    o[h * 4 + 1] = a[h * 2 + 0].y;
    o[h * 4 + 2] = a[h * 2 + 1].x;
    o[h * 4 + 3] = a[h * 2 + 1].y;
  }
  if (SIG) {
#pragma unroll
    for (int h = 0; h < 4; ++h) {
      float4 bb = *(const float4*)(b + c16 + h * 4);
      o[h * 4 + 0] = sigmoidf(o[h * 4 + 0] + bb.x);
      o[h * 4 + 1] = sigmoidf(o[h * 4 + 1] + bb.y);
      o[h * 4 + 2] = sigmoidf(o[h * 4 + 2] + bb.z);
      o[h * 4 + 3] = sigmoidf(o[h * 4 + 3] + bb.w);
    }
  }
  uint4 pk;
  pk.x = pk4_fp8(o[0], o[1], o[2], o[3]);
  pk.y = pk4_fp8(o[4], o[5], o[6], o[7]);
  pk.z = pk4_fp8(o[8], o[9], o[10], o[11]);
  pk.w = pk4_fp8(o[12], o[13], o[14], o[15]);
  *(uint4*)(dst + (size_t)r * HID + c16) = pk;
}

template <bool SIG>
__global__ __launch_bounds__(256) void gather128_kernel(
    const u32* __restrict__ ptr, const int2* __restrict__ ent,
    const u8* __restrict__ src, const float* __restrict__ b,
    u8* __restrict__ dst, int S) {
  long long t = (long long)blockIdx.x * 256 + threadIdx.x;
  gather_body<SIG>(t, ptr, ent, src, b, dst, S);
}

// gatherE (layer 1) with segV merged in as trailing blocks — segV (ent_v
// weight finalization) is independent of the e-side gather, so it backfills
// the latency-bound gather's idle issue slots. Kernel boundary before
// gatherV_L1 guarantees ent_v weights are final.
__global__ __launch_bounds__(256) void gatherE_segV_kernel(
    const u32* __restrict__ ptr_e, const int2* __restrict__ ent_e,
    const u8* __restrict__ src, const float* __restrict__ b,
    u8* __restrict__ dst, int nbGather,
    const u32* __restrict__ ptr_v, int2* __restrict__ ent_v,
    const float* __restrict__ e_card) {
  if ((int)blockIdx.x >= nbGather) {
    // ---- segV role: v-side weights, 2 lanes per segment ----
    int t = ((int)blockIdx.x - nbGather) * 256 + threadIdx.x;
    int i = t >> 1;
    int half = t & 1;
    if (i >= N_NODES) return;
    u32 b0 = ptr_v[i], e0 = ptr_v[i + 1];
    float s = 0.f;
    for (u32 j = b0 + half; j < e0; j += 2) {
      int2 en = ent_v[j];
      s += __int_as_float(en.y) * e_card[en.x];
    }
    s += __shfl_xor(s, 1);
    float inv = 1.f / s;
    for (u32 j = b0 + half; j < e0; j += 2) {
      int2 en = ent_v[j];
      ent_v[j].y = __float_as_int(__int_as_float(en.y) * e_card[en.x] * inv);
    }
    return;
  }
  long long t = (long long)blockIdx.x * 256 + threadIdx.x;
  gather_body<true>(t, ptr_e, ent_e, src, b, dst, N_EDGES);
}

// ---- head ---------------------------------------------------------------

__global__ __launch_bounds__(128) void final_kernel(
    const u32* __restrict__ pooled, const float* __restrict__ lin_w,
    const float* __restrict__ lin_b, float* __restrict__ out) {
  __shared__ float red[64];
  int t = threadIdx.x;
  float v = __uint_as_float(pooled[t]) * lin_w[t];
  if (t >= 64) red[t - 64] = v;
  __syncthreads();
  if (t < 64) {
    v += red[t];
#pragma unroll
    for (int off = 32; off > 0; off >>= 1) v += __shfl_down(v, off);
    if (t == 0) out[0] = v + lin_b[0];
  }
}

__global__ void diag_kernel(float* out, float v) { out[0] = v; }

// ---- launch -----------------------------------------------------------------

extern "C" void kernel_launch(void* const* d_in, const int* in_sizes, int n_in,
                              void* d_out, int out_size, void* d_ws, size_t ws_size,
                              hipStream_t stream) {
  const float* x0     = (const float*)d_in[0];
  const int*   rows   = (const int*)d_in[1];
  const int*   cols   = (const int*)d_in[2];
  const float* vals   = (const float*)d_in[3];
  const float* w0_l1  = (const float*)d_in[4];
  const float* w1_l1  = (const float*)d_in[5];
  const float* b1_l1  = (const float*)d_in[6];
  const float* b0_l1  = (const float*)d_in[7];
  const float* w0_l2  = (const float*)d_in[8];
  const float* w1_l2  = (const float*)d_in[9];
  const float* b1_l2  = (const float*)d_in[10];
  const float* b0_l2  = (const float*)d_in[11];
  const float* lin_w  = (const float*)d_in[12];
  const float* lin_b  = (const float*)d_in[13];
  float* out = (float*)d_out;
  const int nnz = in_sizes[1];

  char* wsp = (char*)d_ws;
  size_t off = 0;
  auto carve = [&](size_t bytes) -> char* {
    char* p = wsp + off;
    off = (off + bytes + 511) & ~(size_t)511;
    return p;
  };
  float* n_card  = (float*)carve((size_t)N_NODES * 4);
  float* e_card  = (float*)carve((size_t)N_EDGES * 4);
  u32*   ptr_v   = (u32*)carve((size_t)(N_NODES + 1) * 4);
  u32*   ptr_e   = (u32*)carve((size_t)(N_EDGES + 1) * 4);
  u32*   bkE     = (u32*)carve((NB_E + 1) * 4);   // counts -> bases (adjacent:
  u32*   bkV     = (u32*)carve((NB_V + 1) * 4);   //  one memset covers both)
  int2*  ent_v   = (int2*)carve((size_t)nnz * 8);   // {idx, val->weight}
  int2*  ent_e   = (int2*)carve((size_t)nnz * 8);
  u32*   pooled  = (u32*)carve(HID * 4);
  u8*    bufN    = (u8*)carve((size_t)N_NODES * HID);        // 25.6 MB fp8
  u8*    bufE    = (u8*)carve((size_t)N_EDGES * HID);        // 51.2 MB fp8
  int2*  tmp_e   = (int2*)carve((size_t)NB_E * CAP_E * 8);   // 19.2 MB slabs
  int2*  tmp_v   = (int2*)carve((size_t)NB_V * CAP_V * 8);   // 16.1 MB slabs

  if (off > ws_size) {  // diagnostic: report ws MB via absmax instead of crashing
    diag_kernel<<<1, 1, 0, stream>>>(out, (float)(ws_size >> 20));
    return;
  }

  // single memset spanning bkE..bkV (adjacent carves incl. 512B padding)
  hipMemsetAsync(bkE, 0, (size_t)((char*)ent_v - (char*)bkE), stream);

  const int nbBin = (nnz + BINSZ - 1) / BINSZ;
  const int nbMM14 = (N_NODES + 7) / 8;

  // CSR build (+ mm14 backfill) -> scans -> build
  bin_mm14_kernel<<<nbBin + nbMM14, 256, 0, stream>>>(
      rows, cols, vals, bkE, bkV, tmp_e, tmp_v, nnz, nbBin,
      x0, w0_l1, bufN, N_NODES);
  scan_all_kernel<<<3, 512, 0, stream>>>(bkE, bkV, ptr_e, ptr_v, pooled, (u32)nnz);
  build_kernel<false><<<NB_V, 512, 0, stream>>>(tmp_v, CAP_V, bkV, ptr_v,
                                                ent_v, n_card, nullptr, N_NODES);
  build_kernel<true><<<NB_E, 512, 0, stream>>>(tmp_e, CAP_E, bkE, ptr_e,
                                               ent_e, e_card, n_card, N_EDGES);

  const int nbE8 = (int)(((long long)N_EDGES * 8 + 255) / 256);
  const int nbN8 = (int)(((long long)N_NODES * 8 + 255) / 256);
  const int nbSegV = (2 * N_NODES + 255) / 256;

  // ---- layer 1 ----
  // gatherE (sigmoid) with segV merged as trailing blocks
  gatherE_segV_kernel<<<nbE8 + nbSegV, 256, 0, stream>>>(
      ptr_e, ent_e, bufN, b1_l1, bufE, nbE8, ptr_v, ent_v, e_card);
  gather128_kernel<false><<<nbN8, 256, 0, stream>>>(ptr_v, ent_v, bufE,
                                                    nullptr, bufN, N_NODES);
  im128_mfma_kernel<true, false><<<1024, 256, 0, stream>>>(bufN, w1_l1, b0_l1,
                                                           nullptr, N_NODES);

  // ---- layer 2 ----
  im128_mfma_kernel<false, false><<<1024, 256, 0, stream>>>(bufN, w0_l2, nullptr,
                                                            nullptr, N_NODES);
  gather128_kernel<true><<<nbE8, 256, 0, stream>>>(ptr_e, ent_e, bufN,
                                                   b1_l2, bufE, N_EDGES);
  gather128_kernel<false><<<nbN8, 256, 0, stream>>>(ptr_v, ent_v, bufE,
                                                    nullptr, bufN, N_NODES);
  im128_mfma_kernel<true, true><<<1024, 256, 0, stream>>>(bufN, w1_l2, b0_l2,
                                                          pooled, N_NODES);

  // ---- head ----
  final_kernel<<<1, 128, 0, stream>>>(pooled, lin_w, lin_b, out);
}